// Round 1
// baseline (2279.596 us; speedup 1.0000x reference)
//
#include <hip/hip_runtime.h>
#include <math.h>

#define CDIM 768
#define INNER 96
#define S49 49
#define MROWS 6272      // 128*49
#define LDV 100         // padded LDS row stride for 96-wide mats
#define LDSC 52         // scores row stride
#define SCALE 0.10206207261596577f  // 1/sqrt(96)

// ---------------------------------------------------------------------------
// GEMM1: H[m,n] = relu( sum_k X[m,k] * W[k,n] ),  X gathered from feat[B,C,S]
// M=6272, N=768, K=768.  64x64 tile, 4x4 per thread.
// ---------------------------------------------------------------------------
__global__ __launch_bounds__(256) void gemm1_relu(const float* __restrict__ feat,
                                                  const float* __restrict__ W,
                                                  float* __restrict__ H) {
  __shared__ float As[64][17];
  __shared__ float Bs[16][64];
  const int t = threadIdx.x;
  const int tx = t & 15, ty = t >> 4;
  const int m0 = blockIdx.x * 64, n0 = blockIdx.y * 64;
  float acc[4][4] = {};

  const int i = t & 63;            // A-tile row
  const int jhi = (t >> 6) * 4;    // A-tile col group
  const int m = m0 + i;
  const int b = m / 49, s = m - b * 49;
  const float* fp = feat + (size_t)b * (CDIM * S49) + s;
  const int colB = t & 63, rhiB = (t >> 6) * 4;

  for (int k0 = 0; k0 < CDIM; k0 += 16) {
    __syncthreads();
#pragma unroll
    for (int jj = 0; jj < 4; jj++)
      As[i][jhi + jj] = fp[(size_t)(k0 + jhi + jj) * S49];
#pragma unroll
    for (int ii = 0; ii < 4; ii++)
      Bs[rhiB + ii][colB] = W[(size_t)(k0 + rhiB + ii) * CDIM + n0 + colB];
    __syncthreads();
#pragma unroll
    for (int kk = 0; kk < 16; kk++) {
      float a[4];
#pragma unroll
      for (int r = 0; r < 4; r++) a[r] = As[ty * 4 + r][kk];
      const float4 bv = *(const float4*)&Bs[kk][tx * 4];
#pragma unroll
      for (int r = 0; r < 4; r++) {
        acc[r][0] += a[r] * bv.x;
        acc[r][1] += a[r] * bv.y;
        acc[r][2] += a[r] * bv.z;
        acc[r][3] += a[r] * bv.w;
      }
    }
  }
#pragma unroll
  for (int r = 0; r < 4; r++) {
    float4 v;
    v.x = fmaxf(acc[r][0], 0.f);
    v.y = fmaxf(acc[r][1], 0.f);
    v.z = fmaxf(acc[r][2], 0.f);
    v.w = fmaxf(acc[r][3], 0.f);
    *(float4*)&H[(size_t)(m0 + ty * 4 + r) * CDIM + n0 + tx * 4] = v;
  }
}

// ---------------------------------------------------------------------------
// GEMM2: O[m,e] = sum_k H[m,k] * W2[k,e].  M=6272, N=96, K=768.
// 64x96 tile, 4x6 per thread.
// ---------------------------------------------------------------------------
__global__ __launch_bounds__(256) void gemm2(const float* __restrict__ H,
                                             const float* __restrict__ W2,
                                             float* __restrict__ O) {
  __shared__ float As[64][17];
  __shared__ float Bs[16][96];
  const int t = threadIdx.x;
  const int tx = t & 15, ty = t >> 4;
  const int m0 = blockIdx.x * 64;
  float acc[4][6] = {};
  const int j4 = (t & 3) * 4, ia = t >> 2;

  for (int k0 = 0; k0 < CDIM; k0 += 16) {
    __syncthreads();
    {
      float4 av = *(const float4*)&H[(size_t)(m0 + ia) * CDIM + k0 + j4];
      As[ia][j4 + 0] = av.x; As[ia][j4 + 1] = av.y;
      As[ia][j4 + 2] = av.z; As[ia][j4 + 3] = av.w;
    }
#pragma unroll
    for (int it = 0; it < 6; it++) {
      int idx = t + it * 256;                 // 16*96 = 1536 elements
      int row = idx / 96, col = idx - row * 96;
      Bs[row][col] = W2[(size_t)(k0 + row) * INNER + col];
    }
    __syncthreads();
#pragma unroll
    for (int kk = 0; kk < 16; kk++) {
      float a[4];
#pragma unroll
      for (int r = 0; r < 4; r++) a[r] = As[ty * 4 + r][kk];
      float bv[6];
#pragma unroll
      for (int c = 0; c < 6; c++) bv[c] = Bs[kk][tx * 6 + c];
#pragma unroll
      for (int r = 0; r < 4; r++)
#pragma unroll
        for (int c = 0; c < 6; c++) acc[r][c] += a[r] * bv[c];
    }
  }
#pragma unroll
  for (int r = 0; r < 4; r++)
#pragma unroll
    for (int c = 0; c < 6; c++)
      O[(size_t)(m0 + ty * 4 + r) * INNER + tx * 6 + c] = acc[r][c];
}

// ---------------------------------------------------------------------------
// Attention + cosine, one block per (bb, aa) pair.
// ---------------------------------------------------------------------------
__device__ __forceinline__ void load_mat(float* __restrict__ dst,
                                         const float* __restrict__ src, int t) {
  // fill 56 rows x 96 cols (rows >= 49 zeroed), row stride LDV
#pragma unroll
  for (int it = 0; it < 6; it++) {
    int idx = t + it * 256;                   // float4 index, 56*24 = 1344
    if (idx < 1344) {
      int row = idx / 24;
      int e4 = (idx - row * 24) * 4;
      float4 v = make_float4(0.f, 0.f, 0.f, 0.f);
      if (row < S49) v = *(const float4*)(src + row * INNER + e4);
      *(float4*)(dst + row * LDV + e4) = v;
    }
  }
}

__global__ __launch_bounds__(256) void attn(const float* __restrict__ qa,
                                            const float* __restrict__ ka,
                                            const float* __restrict__ va,
                                            const float* __restrict__ qb,
                                            const float* __restrict__ kb,
                                            const float* __restrict__ vb,
                                            float* __restrict__ out) {
  __shared__ __align__(16) float A[56 * LDV];
  __shared__ __align__(16) float Bm[56 * LDV];
  __shared__ float sc[52 * LDSC];
  __shared__ float pdot[52 * 16];
  __shared__ float pnrm[52 * 16];
  __shared__ float cosv[52];
  __shared__ float s_total;

  const int t = threadIdx.x;
  const int tx = t & 15, ty = t >> 4;
  const int pair = blockIdx.x;
  const int bb = pair >> 7, aa = pair & 127;

  if (t == 0) s_total = 0.f;

  const float* Qg[2] = {qa + aa * (S49 * INNER), qb + bb * (S49 * INNER)};
  const float* Kg[2] = {kb + bb * (S49 * INNER), ka + aa * (S49 * INNER)};
  const float* Vg[2] = {vb + bb * (S49 * INNER), va + aa * (S49 * INNER)};
  const float* Rg[2] = {va + aa * (S49 * INNER), vb + bb * (S49 * INNER)};

  for (int dir = 0; dir < 2; dir++) {
    __syncthreads();
    load_mat(A, Qg[dir], t);
    load_mat(Bm, Kg[dir], t);
    __syncthreads();
    // ---- scores = Q @ K^T * SCALE  (49x49, 4x4 per thread over 13x13 tiles)
    if (tx < 13 && ty < 13) {
      float acc[4][4] = {};
      for (int e = 0; e < INNER; e += 4) {
        float4 qv[4], kv[4];
#pragma unroll
        for (int r = 0; r < 4; r++) qv[r] = *(const float4*)&A[(ty * 4 + r) * LDV + e];
#pragma unroll
        for (int c = 0; c < 4; c++) kv[c] = *(const float4*)&Bm[(tx * 4 + c) * LDV + e];
#pragma unroll
        for (int r = 0; r < 4; r++)
#pragma unroll
          for (int c = 0; c < 4; c++)
            acc[r][c] += qv[r].x * kv[c].x + qv[r].y * kv[c].y +
                         qv[r].z * kv[c].z + qv[r].w * kv[c].w;
      }
#pragma unroll
      for (int r = 0; r < 4; r++)
#pragma unroll
        for (int c = 0; c < 4; c++) {
          int q = ty * 4 + r, k = tx * 4 + c;
          sc[q * LDSC + k] = (q < S49 && k < S49) ? acc[r][c] * SCALE : 0.f;
        }
    }
    __syncthreads();
    // ---- overwrite A <- V, Bm <- R while 49 threads do row softmax on sc.
    // No normalization: cosine is invariant to positive row scaling.
    load_mat(A, Vg[dir], t);
    load_mat(Bm, Rg[dir], t);
    if (t < S49) {
      float mx = -1e30f;
      for (int k = 0; k < S49; k++) mx = fmaxf(mx, sc[t * LDSC + k]);
      for (int k = 0; k < S49; k++) sc[t * LDSC + k] = __expf(sc[t * LDSC + k] - mx);
    }
    __syncthreads();
    // ---- aligned = P @ V (unnormalized) + cosine partials vs R
    if (ty < 13) {
      const int e0 = tx * 6;
      float acc2[4][6] = {};
      for (int k = 0; k < S49; k++) {
        float pr[4];
#pragma unroll
        for (int r = 0; r < 4; r++) pr[r] = sc[(ty * 4 + r) * LDSC + k];
        float vv[6];
#pragma unroll
        for (int c = 0; c < 6; c++) vv[c] = A[k * LDV + e0 + c];
#pragma unroll
        for (int r = 0; r < 4; r++)
#pragma unroll
          for (int c = 0; c < 6; c++) acc2[r][c] += pr[r] * vv[c];
      }
#pragma unroll
      for (int r = 0; r < 4; r++) {
        int q = ty * 4 + r;
        float d = 0.f, n = 0.f;
#pragma unroll
        for (int c = 0; c < 6; c++) {
          float al = acc2[r][c];
          d += al * Bm[q * LDV + e0 + c];
          n += al * al;
        }
        pdot[q * 16 + tx] = d;
        pnrm[q * 16 + tx] = n;
      }
    }
    __syncthreads();
    // ---- finalize cosine per row
    if (t < S49) {
      float d = 0.f, n = 0.f;
      for (int x = 0; x < 16; x++) { d += pdot[t * 16 + x]; n += pnrm[t * 16 + x]; }
      float nr2 = 0.f;
      for (int e = 0; e < INNER; e++) { float v = Bm[t * LDV + e]; nr2 += v * v; }
      float na = sqrtf(n);
      float nr = sqrtf(nr2);
      cosv[t] = d / (fmaxf(na, 1e-30f) * fmaxf(nr, 1e-8f));
    }
    __syncthreads();
    if (t == 0) {
      float s2 = 0.f;
      for (int q = 0; q < S49; q++) s2 += cosv[q];
      s_total += s2;
    }
  }
  __syncthreads();
  if (t == 0) out[pair] = s_total * (1.f / 49.f);
}

// ---------------------------------------------------------------------------
extern "C" void kernel_launch(void* const* d_in, const int* in_sizes, int n_in,
                              void* d_out, int out_size, void* d_ws, size_t ws_size,
                              hipStream_t stream) {
  const float* fa  = (const float*)d_in[0];
  const float* fb  = (const float*)d_in[1];
  const float* Wq1 = (const float*)d_in[2];
  const float* Wq2 = (const float*)d_in[3];
  const float* Wk1 = (const float*)d_in[4];
  const float* Wk2 = (const float*)d_in[5];
  const float* Wv1 = (const float*)d_in[6];
  const float* Wv2 = (const float*)d_in[7];
  float* out = (float*)d_out;

  float* ws = (float*)d_ws;
  float* hidden = ws;                         // 6272*768
  float* qa = ws + (size_t)MROWS * CDIM;      // each 6272*96
  float* ka = qa + (size_t)MROWS * INNER;
  float* va = ka + (size_t)MROWS * INNER;
  float* qb = va + (size_t)MROWS * INNER;
  float* kb = qb + (size_t)MROWS * INNER;
  float* vb = kb + (size_t)MROWS * INNER;

  struct Job { const float* f; const float* w1; const float* w2; float* o; };
  Job jobs[6] = {
    {fa, Wq1, Wq2, qa}, {fa, Wk1, Wk2, ka}, {fa, Wv1, Wv2, va},
    {fb, Wq1, Wq2, qb}, {fb, Wk1, Wk2, kb}, {fb, Wv1, Wv2, vb},
  };
  dim3 g1(MROWS / 64, CDIM / 64);
  for (int p = 0; p < 6; p++) {
    gemm1_relu<<<g1, 256, 0, stream>>>(jobs[p].f, jobs[p].w1, hidden);
    gemm2<<<MROWS / 64, 256, 0, stream>>>(hidden, jobs[p].w2, jobs[p].o);
  }
  attn<<<128 * 128, 256, 0, stream>>>(qa, ka, va, qb, kb, vb, out);
}

// Round 2
// 691.365 us; speedup vs baseline: 3.2972x; 3.2972x over previous
//
#include <hip/hip_runtime.h>
#include <math.h>

typedef __attribute__((ext_vector_type(8))) short bf16x8;
typedef __attribute__((ext_vector_type(4))) float f32x4;

#define MROWS 12544      // (128+128)*49
#define CDIM 768
#define INNER 96
#define S49 49
#define SCALE 0.10206207261596577f  // 1/sqrt(96)

__device__ __forceinline__ unsigned short f2bf(float f) {
  union { float f; unsigned u; } v; v.f = f;
  unsigned u = v.u;
  return (unsigned short)((u + 0x7fffu + ((u >> 16) & 1u)) >> 16);
}
__device__ __forceinline__ float bf2f(unsigned short h) {
  union { unsigned u; float f; } v; v.u = ((unsigned)h) << 16;
  return v.f;
}

// ---------------------------------------------------------------------------
// prep_x: feat[img][C][S] fp32 -> X[(imgbase+img)*49+s][C] bf16 (LDS transpose)
// ---------------------------------------------------------------------------
__global__ __launch_bounds__(256) void prep_x(const float* __restrict__ feat,
                                              unsigned short* __restrict__ X,
                                              int imgbase) {
  __shared__ float T[64][50];
  const int t = threadIdx.x;
  const int ct = blockIdx.x;   // 0..11 (C tiles of 64)
  const int img = blockIdx.y;  // 0..127
  const float* src = feat + (size_t)img * (CDIM * S49) + (size_t)ct * 64 * S49;
  for (int idx = t; idx < 64 * S49; idx += 256) {
    int cc = idx / S49, s = idx - cc * S49;
    T[cc][s] = src[cc * S49 + s];
  }
  __syncthreads();
  unsigned short* dst = X + (size_t)(imgbase + img) * S49 * CDIM + ct * 64;
  for (int idx = t; idx < S49 * 64; idx += 256) {
    int s = idx >> 6, cc = idx & 63;
    dst[(size_t)s * CDIM + cc] = f2bf(T[cc][s]);
  }
}

// ---------------------------------------------------------------------------
// prep_wT: src[R][C] fp32 -> dst[C][R] bf16 (R,C multiples of 32)
// ---------------------------------------------------------------------------
__global__ __launch_bounds__(256) void prep_wT(const float* __restrict__ src,
                                               unsigned short* __restrict__ dst,
                                               int R, int C) {
  __shared__ float T[32][33];
  const int c0 = blockIdx.x * 32, r0 = blockIdx.y * 32;
  const int t = threadIdx.x;
  for (int idx = t; idx < 1024; idx += 256) {
    int rr = idx >> 5, cc = idx & 31;
    T[rr][cc] = src[(size_t)(r0 + rr) * C + c0 + cc];
  }
  __syncthreads();
  for (int idx = t; idx < 1024; idx += 256) {
    int rr = idx >> 5, cc = idx & 31;
    dst[(size_t)(c0 + rr) * R + r0 + cc] = f2bf(T[cc][rr]);
  }
}

// ---------------------------------------------------------------------------
// GEMM1: H = relu(X @ W1), bf16 MFMA. M=12544, N=768, K=768. 64x64 tile.
// LDS strides padded to 72 ushorts (36 words -> 2-way max bank aliasing).
// ---------------------------------------------------------------------------
#define LDK 72
__global__ __launch_bounds__(256) void gemm1(const unsigned short* __restrict__ X,
                                             const unsigned short* __restrict__ W1T,
                                             unsigned short* __restrict__ H) {
  __shared__ unsigned short As[64 * LDK];
  __shared__ unsigned short Bs[64 * LDK];
  const int t = threadIdx.x;
  const int lane = t & 63, w = t >> 6;
  const int lr = lane & 15, lq = lane >> 4;
  const int wm = w & 1, wn = w >> 1;
  const int m0 = blockIdx.x * 64, n0 = blockIdx.y * 64;
  const f32x4 z4 = {0.f, 0.f, 0.f, 0.f};
  f32x4 acc[2][2] = {{z4, z4}, {z4, z4}};

  for (int k0 = 0; k0 < CDIM; k0 += 64) {
    __syncthreads();
    for (int c = t; c < 512; c += 256) {
      int r = c >> 3, kc = (c & 7) * 8;
      *(uint4*)(As + r * LDK + kc) = *(const uint4*)(X + (size_t)(m0 + r) * CDIM + k0 + kc);
      *(uint4*)(Bs + r * LDK + kc) = *(const uint4*)(W1T + (size_t)(n0 + r) * CDIM + k0 + kc);
    }
    __syncthreads();
#pragma unroll
    for (int kk = 0; kk < 2; kk++) {
      bf16x8 af[2], bfr[2];
#pragma unroll
      for (int mt = 0; mt < 2; mt++)
        af[mt] = *(const bf16x8*)(As + (wm * 32 + mt * 16 + lr) * LDK + kk * 32 + lq * 8);
#pragma unroll
      for (int nt = 0; nt < 2; nt++)
        bfr[nt] = *(const bf16x8*)(Bs + (wn * 32 + nt * 16 + lr) * LDK + kk * 32 + lq * 8);
#pragma unroll
      for (int mt = 0; mt < 2; mt++)
#pragma unroll
        for (int nt = 0; nt < 2; nt++)
          acc[mt][nt] = __builtin_amdgcn_mfma_f32_16x16x32_bf16(af[mt], bfr[nt], acc[mt][nt], 0, 0, 0);
    }
  }
#pragma unroll
  for (int mt = 0; mt < 2; mt++)
#pragma unroll
    for (int nt = 0; nt < 2; nt++)
#pragma unroll
      for (int r = 0; r < 4; r++) {
        int m = m0 + wm * 32 + mt * 16 + lq * 4 + r;
        int n = n0 + wn * 32 + nt * 16 + lr;
        H[(size_t)m * CDIM + n] = f2bf(fmaxf(acc[mt][nt][r], 0.f));
      }
}

// ---------------------------------------------------------------------------
// GEMM2: O = H @ W2. M=12544, N=96, K=768. 64x96 tile (wave = 16 rows x 96).
// isV: also write Vt[img][e][64] (keys zero-padded globally) and vnorm[m].
// ---------------------------------------------------------------------------
__global__ __launch_bounds__(256) void gemm2(const unsigned short* __restrict__ H,
                                             const unsigned short* __restrict__ W2T,
                                             unsigned short* __restrict__ O,
                                             unsigned short* __restrict__ Vt,
                                             float* __restrict__ vnorm,
                                             int isV) {
  __shared__ unsigned short As[64 * LDK];
  __shared__ unsigned short Bs[96 * LDK];
  const int t = threadIdx.x;
  const int lane = t & 63, w = t >> 6;
  const int lr = lane & 15, lq = lane >> 4;
  const int m0 = blockIdx.x * 64;
  const f32x4 z4 = {0.f, 0.f, 0.f, 0.f};
  f32x4 acc[6] = {z4, z4, z4, z4, z4, z4};

  for (int k0 = 0; k0 < CDIM; k0 += 64) {
    __syncthreads();
    for (int c = t; c < 512; c += 256) {
      int r = c >> 3, kc = (c & 7) * 8;
      *(uint4*)(As + r * LDK + kc) = *(const uint4*)(H + (size_t)(m0 + r) * CDIM + k0 + kc);
    }
    for (int c = t; c < 768; c += 256) {
      int r = c >> 3, kc = (c & 7) * 8;
      *(uint4*)(Bs + r * LDK + kc) = *(const uint4*)(W2T + (size_t)r * CDIM + k0 + kc);
    }
    __syncthreads();
#pragma unroll
    for (int kk = 0; kk < 2; kk++) {
      bf16x8 a = *(const bf16x8*)(As + (w * 16 + lr) * LDK + kk * 32 + lq * 8);
#pragma unroll
      for (int nt = 0; nt < 6; nt++) {
        bf16x8 b = *(const bf16x8*)(Bs + (nt * 16 + lr) * LDK + kk * 32 + lq * 8);
        acc[nt] = __builtin_amdgcn_mfma_f32_16x16x32_bf16(a, b, acc[nt], 0, 0, 0);
      }
    }
  }
  float nsq[4] = {0.f, 0.f, 0.f, 0.f};
#pragma unroll
  for (int nt = 0; nt < 6; nt++)
#pragma unroll
    for (int r = 0; r < 4; r++) {
      int m = m0 + w * 16 + lq * 4 + r;
      int e = nt * 16 + lr;
      float v = acc[nt][r];
      O[(size_t)m * INNER + e] = f2bf(v);
      if (isV) {
        int img = m / 49, s = m - img * 49;
        Vt[(size_t)img * (INNER * 64) + e * 64 + s] = f2bf(v);
        nsq[r] += v * v;
      }
    }
  if (isV) {
#pragma unroll
    for (int r = 0; r < 4; r++) {
      float p = nsq[r];
      p += __shfl_xor(p, 1, 16);
      p += __shfl_xor(p, 2, 16);
      p += __shfl_xor(p, 4, 16);
      p += __shfl_xor(p, 8, 16);
      if (lr == 0) vnorm[m0 + w * 16 + lq * 4 + r] = sqrtf(p);
    }
  }
}

// ---------------------------------------------------------------------------
// attn: one block per (bb,aa) pair. MFMA QK^T and PV, fp32 softmax (no row-sum
// normalization: cosine is scale invariant), cosine epilogue in registers.
// ---------------------------------------------------------------------------
#define LQS 104   // 52 words: 2-way max
#define LVS 72    // 36 words: 2-way max
#define LSC 68
__global__ __launch_bounds__(256) void attn(const unsigned short* __restrict__ Q,
                                            const unsigned short* __restrict__ K,
                                            const unsigned short* __restrict__ V,
                                            const unsigned short* __restrict__ Vt,
                                            const float* __restrict__ vnorm,
                                            float* __restrict__ out) {
  __shared__ unsigned short Qs[64 * LQS];
  __shared__ unsigned short Ks[64 * LQS];
  __shared__ unsigned short Vn[64 * LQS];   // reference R (normal layout)
  __shared__ unsigned short Vts[96 * LVS];  // V transposed [e][key], keys padded 0
  __shared__ unsigned short Ps[64 * LVS];   // exp(scores) bf16
  __shared__ float sc[S49 * LSC];
  __shared__ float rmax4[64][4];
  __shared__ float vnR[64];
  __shared__ float total;

  const int t = threadIdx.x;
  const int lane = t & 63, w = t >> 6;
  const int lr = lane & 15, lq = lane >> 4;
  const int pair = blockIdx.x;
  const int bb = pair >> 7, aa = pair & 127;
  if (t == 0) total = 0.f;

  const int rowA = aa * S49, rowB = (128 + bb) * S49;
  // dir0: Q=qa,K=kb,V=vb,R=va ; dir1: Q=qb,K=ka,V=va,R=vb
  const int qrow[2] = {rowA, rowB};
  const int krow[2] = {rowB, rowA};
  const int vimg[2] = {128 + bb, aa};
  const int rrow[2] = {rowA, rowB};

  for (int dir = 0; dir < 2; dir++) {
    __syncthreads();
    {
      const unsigned short* qg = Q + (size_t)qrow[dir] * INNER;
      const unsigned short* kg = K + (size_t)krow[dir] * INNER;
      const unsigned short* rg = V + (size_t)rrow[dir] * INNER;
      for (int c = t; c < 588; c += 256) {       // 49 rows x 12 chunks
        int r = c / 12, kc = (c - r * 12) * 8;
        *(uint4*)(Qs + r * LQS + kc) = *(const uint4*)(qg + r * INNER + kc);
        *(uint4*)(Ks + r * LQS + kc) = *(const uint4*)(kg + r * INNER + kc);
        *(uint4*)(Vn + r * LQS + kc) = *(const uint4*)(rg + r * INNER + kc);
      }
      const unsigned short* vg = Vt + (size_t)vimg[dir] * (INNER * 64);
      for (int c = t; c < 768; c += 256) {       // 96 rows x 8 chunks
        int r = c >> 3, kc = (c & 7) * 8;
        *(uint4*)(Vts + r * LVS + kc) = *(const uint4*)(vg + r * 64 + kc);
      }
      if (t < S49) vnR[t] = vnorm[rrow[dir] + t];
    }
    __syncthreads();
    // ---- QK^T via MFMA: wave w = q-tile w; 4 key-tiles; K-dim e (3 steps)
    {
      const f32x4 z4 = {0.f, 0.f, 0.f, 0.f};
      f32x4 a4[4] = {z4, z4, z4, z4};
#pragma unroll
      for (int ks = 0; ks < 3; ks++) {
        bf16x8 a = *(const bf16x8*)(Qs + (w * 16 + lr) * LQS + ks * 32 + lq * 8);
#pragma unroll
        for (int kt = 0; kt < 4; kt++) {
          bf16x8 b = *(const bf16x8*)(Ks + (kt * 16 + lr) * LQS + ks * 32 + lq * 8);
          a4[kt] = __builtin_amdgcn_mfma_f32_16x16x32_bf16(a, b, a4[kt], 0, 0, 0);
        }
      }
      const int row = w * 16 + lq * 4;
#pragma unroll
      for (int r = 0; r < 4; r++)
        if (row + r < S49) {
#pragma unroll
          for (int kt = 0; kt < 4; kt++)
            sc[(row + r) * LSC + kt * 16 + lr] = a4[kt][r] * SCALE;
        }
    }
    __syncthreads();
    // ---- row max partials (4 threads per row)
    {
      int row = t >> 2, sub = t & 3;
      if (row < S49) {
        float m = -1e30f;
        for (int k = sub; k < S49; k += 4) m = fmaxf(m, sc[row * LSC + k]);
        rmax4[row][sub] = m;
      }
    }
    __syncthreads();
    // ---- exp -> Ps (bf16, unnormalized; rows/keys >=49 zeroed)
    {
      int row = t >> 2, k0 = (t & 3) * 16;
      float mx = fmaxf(fmaxf(rmax4[row][0], rmax4[row][1]),
                       fmaxf(rmax4[row][2], rmax4[row][3]));
#pragma unroll
      for (int j = 0; j < 16; j++) {
        int key = k0 + j;
        float v = 0.f;
        if (row < S49 && key < S49) v = __expf(sc[row * LSC + key] - mx);
        Ps[row * LVS + key] = f2bf(v);
      }
    }
    __syncthreads();
    // ---- PV via MFMA + cosine epilogue
    {
      const f32x4 z4 = {0.f, 0.f, 0.f, 0.f};
      f32x4 pv[6] = {z4, z4, z4, z4, z4, z4};
#pragma unroll
      for (int ks = 0; ks < 2; ks++) {
        bf16x8 a = *(const bf16x8*)(Ps + (w * 16 + lr) * LVS + ks * 32 + lq * 8);
#pragma unroll
        for (int et = 0; et < 6; et++) {
          bf16x8 b = *(const bf16x8*)(Vts + (et * 16 + lr) * LVS + ks * 32 + lq * 8);
          pv[et] = __builtin_amdgcn_mfma_f32_16x16x32_bf16(a, b, pv[et], 0, 0, 0);
        }
      }
      float part = 0.f;
#pragma unroll
      for (int r = 0; r < 4; r++) {
        int q = w * 16 + lq * 4 + r;
        float d = 0.f, nn = 0.f;
#pragma unroll
        for (int et = 0; et < 6; et++) {
          float al = pv[et][r];
          d += al * bf2f(Vn[q * LQS + et * 16 + lr]);
          nn += al * al;
        }
        d += __shfl_xor(d, 1, 16); d += __shfl_xor(d, 2, 16);
        d += __shfl_xor(d, 4, 16); d += __shfl_xor(d, 8, 16);
        nn += __shfl_xor(nn, 1, 16); nn += __shfl_xor(nn, 2, 16);
        nn += __shfl_xor(nn, 4, 16); nn += __shfl_xor(nn, 8, 16);
        if (lr == 0 && q < S49) {
          part += d / (fmaxf(sqrtf(nn), 1e-20f) * fmaxf(vnR[q], 1e-8f));
        }
      }
      if (lr == 0) atomicAdd(&total, part);
    }
  }
  __syncthreads();
  if (t == 0) out[pair] = total * (1.f / 49.f);
}

// ---------------------------------------------------------------------------
extern "C" void kernel_launch(void* const* d_in, const int* in_sizes, int n_in,
                              void* d_out, int out_size, void* d_ws, size_t ws_size,
                              hipStream_t stream) {
  const float* fa  = (const float*)d_in[0];
  const float* fb  = (const float*)d_in[1];
  const float* W1[3] = {(const float*)d_in[2], (const float*)d_in[4], (const float*)d_in[6]};
  const float* W2[3] = {(const float*)d_in[3], (const float*)d_in[5], (const float*)d_in[7]};
  float* out = (float*)d_out;

  unsigned short* p = (unsigned short*)d_ws;
  unsigned short* Xbf = p;                 p += (size_t)MROWS * CDIM;     // 19.3 MB
  unsigned short* W1T = p;                 p += (size_t)3 * CDIM * CDIM;  // 3.5 MB
  unsigned short* W2T = p;                 p += (size_t)3 * INNER * CDIM; // 0.44 MB
  unsigned short* H   = p;                 p += (size_t)MROWS * CDIM;     // 19.3 MB
  unsigned short* QKV = p;                 p += (size_t)3 * MROWS * INNER;// 7.2 MB
  unsigned short* Vt  = p;                 p += (size_t)256 * INNER * 64; // 3.1 MB
  float* vnorm = (float*)p;                                              // 50 KB

  prep_x<<<dim3(12, 128), 256, 0, stream>>>(fa, Xbf, 0);
  prep_x<<<dim3(12, 128), 256, 0, stream>>>(fb, Xbf, 128);
  for (int wdx = 0; wdx < 3; wdx++) {
    prep_wT<<<dim3(24, 24), 256, 0, stream>>>(W1[wdx], W1T + (size_t)wdx * CDIM * CDIM, CDIM, CDIM);
    prep_wT<<<dim3(3, 24), 256, 0, stream>>>(W2[wdx], W2T + (size_t)wdx * INNER * CDIM, CDIM, INNER);
  }
  hipMemsetAsync(Vt, 0, (size_t)256 * INNER * 64 * 2, stream);
  for (int wdx = 0; wdx < 3; wdx++) {
    gemm1<<<dim3(MROWS / 64, CDIM / 64), 256, 0, stream>>>(
        Xbf, W1T + (size_t)wdx * CDIM * CDIM, H);
    gemm2<<<dim3(MROWS / 64), 256, 0, stream>>>(
        H, W2T + (size_t)wdx * INNER * CDIM, QKV + (size_t)wdx * MROWS * INNER,
        Vt, vnorm, wdx == 2 ? 1 : 0);
  }
  attn<<<dim3(128 * 128), 256, 0, stream>>>(
      QKV, QKV + (size_t)MROWS * INNER, QKV + (size_t)2 * MROWS * INNER, Vt, vnorm, out);
}

// Round 3
// 550.356 us; speedup vs baseline: 4.1420x; 1.2562x over previous
//
#include <hip/hip_runtime.h>
#include <math.h>

typedef __attribute__((ext_vector_type(8))) short bf16x8;
typedef __attribute__((ext_vector_type(4))) float f32x4;

#define MROWS 12544      // (128+128)*49
#define CDIM 768
#define INNER 96
#define S49 49
#define NSIDE 6272       // 128*49 rows per side
#define SCALE 0.10206207261596577f  // 1/sqrt(96)

__device__ __forceinline__ unsigned short f2bf(float f) {
  union { float f; unsigned u; } v; v.f = f;
  unsigned u = v.u;
  return (unsigned short)((u + 0x7fffu + ((u >> 16) & 1u)) >> 16);
}
__device__ __forceinline__ float bf2f(unsigned short h) {
  union { unsigned u; float f; } v; v.u = ((unsigned)h) << 16;
  return v.f;
}

// async global->LDS, 16B per lane. Dest must be wave-uniform base + lane*16.
__device__ __forceinline__ void gld16(const unsigned short* g, unsigned short* l) {
  __builtin_amdgcn_global_load_lds(
      (const __attribute__((address_space(1))) unsigned int*)(g),
      (__attribute__((address_space(3))) unsigned int*)(l), 16, 0, 0);
}

// ---------------------------------------------------------------------------
// prep_x: feat[img][C][S] fp32 -> X[(imgbase+img)*49+s][C] bf16 (LDS transpose)
// ---------------------------------------------------------------------------
__global__ __launch_bounds__(256) void prep_x(const float* __restrict__ feat,
                                              unsigned short* __restrict__ X,
                                              int imgbase) {
  __shared__ float T[64][50];
  const int t = threadIdx.x;
  const int ct = blockIdx.x;   // 0..11 (C tiles of 64)
  const int img = blockIdx.y;  // 0..127
  const float* src = feat + (size_t)img * (CDIM * S49) + (size_t)ct * 64 * S49;
  for (int idx = t; idx < 64 * S49; idx += 256) {
    int cc = idx / S49, s = idx - cc * S49;
    T[cc][s] = src[cc * S49 + s];
  }
  __syncthreads();
  unsigned short* dst = X + (size_t)(imgbase + img) * S49 * CDIM + ct * 64;
  for (int idx = t; idx < S49 * 64; idx += 256) {
    int s = idx >> 6, cc = idx & 63;
    dst[(size_t)s * CDIM + cc] = f2bf(T[cc][s]);
  }
}

// ---------------------------------------------------------------------------
// prep_wT: src[R][C] fp32 -> dst[C][R] bf16 (R,C multiples of 32)
// ---------------------------------------------------------------------------
__global__ __launch_bounds__(256) void prep_wT(const float* __restrict__ src,
                                               unsigned short* __restrict__ dst,
                                               int R, int C) {
  __shared__ float T[32][33];
  const int c0 = blockIdx.x * 32, r0 = blockIdx.y * 32;
  const int t = threadIdx.x;
  for (int idx = t; idx < 1024; idx += 256) {
    int rr = idx >> 5, cc = idx & 31;
    T[rr][cc] = src[(size_t)(r0 + rr) * C + c0 + cc];
  }
  __syncthreads();
  for (int idx = t; idx < 1024; idx += 256) {
    int rr = idx >> 5, cc = idx & 31;
    dst[(size_t)(c0 + rr) * R + r0 + cc] = f2bf(T[cc][rr]);
  }
}

// ---------------------------------------------------------------------------
// GEMM1 (m97-style): H = relu(X @ W1). M=12544, N=768, K=768.
// 128x128 tile, BK=64, global_load_lds staging, 4 waves each 64x64.
// ---------------------------------------------------------------------------
__global__ __launch_bounds__(256) void gemm1b(const unsigned short* __restrict__ X,
                                              const unsigned short* __restrict__ W1T,
                                              unsigned short* __restrict__ H) {
  __shared__ __align__(16) unsigned short As[128 * 64];
  __shared__ __align__(16) unsigned short Bs[128 * 64];
  const int t = threadIdx.x;
  const int lane = t & 63, w = t >> 6;
  const int lr = lane & 15, lq = lane >> 4;
  const int wm = w & 1, wn = w >> 1;
  const int m0 = blockIdx.x * 128, n0 = blockIdx.y * 128;
  const f32x4 z4 = {0.f, 0.f, 0.f, 0.f};
  f32x4 acc[4][4] = {{z4, z4, z4, z4}, {z4, z4, z4, z4},
                     {z4, z4, z4, z4}, {z4, z4, z4, z4}};

  for (int k0 = 0; k0 < CDIM; k0 += 64) {
    __syncthreads();
#pragma unroll
    for (int j = 0; j < 4; j++) {
      int idx = t + j * 256;               // 0..1023
      int row = idx >> 3, col = (idx & 7) * 8;
      gld16(X + (size_t)(m0 + row) * CDIM + k0 + col, As + idx * 8);
      gld16(W1T + (size_t)(n0 + row) * CDIM + k0 + col, Bs + idx * 8);
    }
    __syncthreads();
#pragma unroll
    for (int ks = 0; ks < 2; ks++) {
      bf16x8 a[4], b[4];
#pragma unroll
      for (int mt = 0; mt < 4; mt++)
        a[mt] = *(const bf16x8*)(As + (wm * 64 + mt * 16 + lr) * 64 + ks * 32 + lq * 8);
#pragma unroll
      for (int nt = 0; nt < 4; nt++)
        b[nt] = *(const bf16x8*)(Bs + (wn * 64 + nt * 16 + lr) * 64 + ks * 32 + lq * 8);
#pragma unroll
      for (int mt = 0; mt < 4; mt++)
#pragma unroll
        for (int nt = 0; nt < 4; nt++)
          acc[mt][nt] = __builtin_amdgcn_mfma_f32_16x16x32_bf16(a[mt], b[nt], acc[mt][nt], 0, 0, 0);
    }
  }
#pragma unroll
  for (int mt = 0; mt < 4; mt++)
#pragma unroll
    for (int nt = 0; nt < 4; nt++)
#pragma unroll
      for (int r = 0; r < 4; r++) {
        int m = m0 + wm * 64 + mt * 16 + lq * 4 + r;
        int n = n0 + wn * 64 + nt * 16 + lr;
        H[(size_t)m * CDIM + n] = f2bf(fmaxf(acc[mt][nt][r], 0.f));
      }
}

// ---------------------------------------------------------------------------
// GEMM2: O = H @ W2. M=12544, N=96, K=768. 64x96 tile (wave = 16 rows x 96).
// isV: also write Vt[img][e][64] (keys zero-padded) and vnorm[m].
// ---------------------------------------------------------------------------
#define LDK 72
__global__ __launch_bounds__(256) void gemm2(const unsigned short* __restrict__ H,
                                             const unsigned short* __restrict__ W2T,
                                             unsigned short* __restrict__ O,
                                             unsigned short* __restrict__ Vt,
                                             float* __restrict__ vnorm,
                                             int isV) {
  __shared__ __align__(16) unsigned short As[64 * LDK];
  __shared__ __align__(16) unsigned short Bs[96 * LDK];
  const int t = threadIdx.x;
  const int lane = t & 63, w = t >> 6;
  const int lr = lane & 15, lq = lane >> 4;
  const int m0 = blockIdx.x * 64;
  const f32x4 z4 = {0.f, 0.f, 0.f, 0.f};
  f32x4 acc[6] = {z4, z4, z4, z4, z4, z4};

  for (int k0 = 0; k0 < CDIM; k0 += 64) {
    __syncthreads();
    for (int c = t; c < 512; c += 256) {
      int r = c >> 3, kc = (c & 7) * 8;
      *(uint4*)(As + r * LDK + kc) = *(const uint4*)(H + (size_t)(m0 + r) * CDIM + k0 + kc);
    }
    for (int c = t; c < 768; c += 256) {
      int r = c >> 3, kc = (c & 7) * 8;
      *(uint4*)(Bs + r * LDK + kc) = *(const uint4*)(W2T + (size_t)r * CDIM + k0 + kc);
    }
    __syncthreads();
#pragma unroll
    for (int kk = 0; kk < 2; kk++) {
      bf16x8 a = *(const bf16x8*)(As + (w * 16 + lr) * LDK + kk * 32 + lq * 8);
#pragma unroll
      for (int nt = 0; nt < 6; nt++) {
        bf16x8 b = *(const bf16x8*)(Bs + (nt * 16 + lr) * LDK + kk * 32 + lq * 8);
        acc[nt] = __builtin_amdgcn_mfma_f32_16x16x32_bf16(a, b, acc[nt], 0, 0, 0);
      }
    }
  }
  float nsq[4] = {0.f, 0.f, 0.f, 0.f};
#pragma unroll
  for (int nt = 0; nt < 6; nt++)
#pragma unroll
    for (int r = 0; r < 4; r++) {
      int m = m0 + w * 16 + lq * 4 + r;
      int e = nt * 16 + lr;
      float v = acc[nt][r];
      O[(size_t)m * INNER + e] = f2bf(v);
      if (isV) {
        int img = m / 49, s = m - img * 49;
        Vt[(size_t)img * (INNER * 64) + e * 64 + s] = f2bf(v);
        nsq[r] += v * v;
      }
    }
  if (isV) {
#pragma unroll
    for (int r = 0; r < 4; r++) {
      float p = nsq[r];
      p += __shfl_xor(p, 1, 16);
      p += __shfl_xor(p, 2, 16);
      p += __shfl_xor(p, 4, 16);
      p += __shfl_xor(p, 8, 16);
      if (lr == 0) vnorm[m0 + w * 16 + lq * 4 + r] = sqrtf(p);
    }
  }
}

// ---------------------------------------------------------------------------
// attn2: batched-query attention+cosine.
// block = (dir, fixed image f, chunk of 128 query rows). 4 waves x 32 q-rows.
// dir0: queries qa, keys kb(f=bb), values vb, ref va  -> cosbuf[(bb)][qrow_a]
// dir1: queries qb, keys ka(f=aa), values va, ref vb  -> cosbuf[(128+aa)][qrow_b]
// Softmax in registers (unnormalized: cosine is scale-invariant).
// ---------------------------------------------------------------------------
#define LQS 104   // 52 words
#define LVS 72    // 36 words
__global__ __launch_bounds__(256) void attn2(const unsigned short* __restrict__ Q,
                                             const unsigned short* __restrict__ K,
                                             const unsigned short* __restrict__ V,
                                             const unsigned short* __restrict__ Vt,
                                             const float* __restrict__ vnorm,
                                             float* __restrict__ cosbuf) {
  __shared__ __align__(16) unsigned short Ks[64 * LQS];
  __shared__ __align__(16) unsigned short Vts[96 * LVS];
  __shared__ __align__(16) unsigned short Qs[128 * LQS];  // queries, then refs
  __shared__ __align__(16) unsigned short Ps[4][32 * LVS];

  const int t = threadIdx.x;
  const int lane = t & 63, w = t >> 6;
  const int lr = lane & 15, lq = lane >> 4;

  int bx = blockIdx.x;
  const int dir = bx / NSIDE; bx -= dir * NSIDE;
  const int f = bx / 49, chunk = bx - f * 49;
  const int r0 = chunk * 128;
  const int qbase = (dir == 0) ? 0 : NSIDE;           // query/ref row base
  const int kbase = ((dir == 0) ? (128 + f) : f) * S49;
  const int vimg  = (dir == 0) ? (128 + f) : f;

  // ---- stage K (zero-pad rows 49..63), Vt, Q
  for (int c = t; c < 768; c += 256) {       // Ks: 64 rows x 12 chunks
    int r = c / 12, kc = (c - r * 12) * 8;
    uint4 v = make_uint4(0u, 0u, 0u, 0u);
    if (r < S49) v = *(const uint4*)(K + (size_t)(kbase + r) * INNER + kc);
    *(uint4*)(Ks + r * LQS + kc) = v;
  }
  for (int c = t; c < 768; c += 256) {       // Vts: 96 rows x 8 chunks
    int r = c >> 3, kc = (c & 7) * 8;
    *(uint4*)(Vts + r * LVS + kc) = *(const uint4*)(Vt + (size_t)vimg * (INNER * 64) + r * 64 + kc);
  }
  for (int c = t; c < 1536; c += 256) {      // Qs: 128 rows x 12 chunks
    int r = c / 12, kc = (c - r * 12) * 8;
    *(uint4*)(Qs + r * LQS + kc) = *(const uint4*)(Q + (size_t)(qbase + r0 + r) * INNER + kc);
  }
  __syncthreads();

  // ---- QK^T: wave w owns q-rows w*32..w*32+31 (2 m-tiles x 4 k-tiles)
  const f32x4 z4 = {0.f, 0.f, 0.f, 0.f};
  f32x4 s[2][4] = {{z4, z4, z4, z4}, {z4, z4, z4, z4}};
#pragma unroll
  for (int ks = 0; ks < 3; ks++) {
    bf16x8 a[2];
#pragma unroll
    for (int mt = 0; mt < 2; mt++)
      a[mt] = *(const bf16x8*)(Qs + (w * 32 + mt * 16 + lr) * LQS + ks * 32 + lq * 8);
#pragma unroll
    for (int kt = 0; kt < 4; kt++) {
      bf16x8 b = *(const bf16x8*)(Ks + (kt * 16 + lr) * LQS + ks * 32 + lq * 8);
#pragma unroll
      for (int mt = 0; mt < 2; mt++)
        s[mt][kt] = __builtin_amdgcn_mfma_f32_16x16x32_bf16(a[mt], b, s[mt][kt], 0, 0, 0);
    }
  }

  // ---- softmax in registers (C layout: col = kt*16+lr, row = mt*16+lq*4+r)
  unsigned short* Pw = &Ps[w][0];
#pragma unroll
  for (int mt = 0; mt < 2; mt++) {
    float mx[4] = {-1e30f, -1e30f, -1e30f, -1e30f};
#pragma unroll
    for (int kt = 0; kt < 4; kt++)
#pragma unroll
      for (int r = 0; r < 4; r++) {
        float v = s[mt][kt][r] * SCALE;
        if (kt == 3 && lr > 0) v = -1e30f;   // cols 49..63 padded
        s[mt][kt][r] = v;
        mx[r] = fmaxf(mx[r], v);
      }
#pragma unroll
    for (int r = 0; r < 4; r++) {
      mx[r] = fmaxf(mx[r], __shfl_xor(mx[r], 1, 16));
      mx[r] = fmaxf(mx[r], __shfl_xor(mx[r], 2, 16));
      mx[r] = fmaxf(mx[r], __shfl_xor(mx[r], 4, 16));
      mx[r] = fmaxf(mx[r], __shfl_xor(mx[r], 8, 16));
    }
#pragma unroll
    for (int kt = 0; kt < 4; kt++)
#pragma unroll
      for (int r = 0; r < 4; r++) {
        float p = (kt == 3 && lr > 0) ? 0.f : __expf(s[mt][kt][r] - mx[r]);
        Pw[(mt * 16 + lq * 4 + r) * LVS + kt * 16 + lr] = f2bf(p);
      }
  }
  __syncthreads();

  // ---- re-stage Qs <- reference V rows (same side as queries)
  for (int c = t; c < 1536; c += 256) {
    int r = c / 12, kc = (c - r * 12) * 8;
    *(uint4*)(Qs + r * LQS + kc) = *(const uint4*)(V + (size_t)(qbase + r0 + r) * INNER + kc);
  }
  __syncthreads();

  // ---- PV: aligned = P @ V  (2 m-tiles x 6 e-tiles, K=64)
  f32x4 pv[2][6] = {{z4, z4, z4, z4, z4, z4}, {z4, z4, z4, z4, z4, z4}};
#pragma unroll
  for (int ks = 0; ks < 2; ks++) {
    bf16x8 a[2];
#pragma unroll
    for (int mt = 0; mt < 2; mt++)
      a[mt] = *(const bf16x8*)(Pw + (mt * 16 + lr) * LVS + ks * 32 + lq * 8);
#pragma unroll
    for (int et = 0; et < 6; et++) {
      bf16x8 b = *(const bf16x8*)(Vts + (et * 16 + lr) * LVS + ks * 32 + lq * 8);
#pragma unroll
      for (int mt = 0; mt < 2; mt++)
        pv[mt][et] = __builtin_amdgcn_mfma_f32_16x16x32_bf16(a[mt], b, pv[mt][et], 0, 0, 0);
    }
  }

  // ---- cosine epilogue (per q-row): dot(aligned, ref), ||aligned||, /||ref||
#pragma unroll
  for (int mt = 0; mt < 2; mt++)
#pragma unroll
    for (int r = 0; r < 4; r++) {
      int row = w * 32 + mt * 16 + lq * 4 + r;
      float d = 0.f, nn = 0.f;
#pragma unroll
      for (int et = 0; et < 6; et++) {
        float al = pv[mt][et][r];
        d += al * bf2f(Qs[row * LQS + et * 16 + lr]);
        nn += al * al;
      }
      d += __shfl_xor(d, 1, 16); d += __shfl_xor(d, 2, 16);
      d += __shfl_xor(d, 4, 16); d += __shfl_xor(d, 8, 16);
      nn += __shfl_xor(nn, 1, 16); nn += __shfl_xor(nn, 2, 16);
      nn += __shfl_xor(nn, 4, 16); nn += __shfl_xor(nn, 8, 16);
      if (lr == 0) {
        float vn = vnorm[qbase + r0 + row];
        float cv = d / (fmaxf(sqrtf(nn), 1e-20f) * fmaxf(vn, 1e-8f));
        cosbuf[(size_t)(dir * 128 + f) * NSIDE + r0 + row] = cv;
      }
    }
}

// ---------------------------------------------------------------------------
// reduce_out: out[bb*128+aa] = (sum_q cos0[bb][aa*49+q] + cos1[aa][bb*49+q])/49
// ---------------------------------------------------------------------------
__global__ __launch_bounds__(256) void reduce_out(const float* __restrict__ cosbuf,
                                                  float* __restrict__ out) {
  const int t = threadIdx.x, lane = t & 63, wv = t >> 6;
  const int pair = blockIdx.x * 4 + wv;
  const int bb = pair >> 7, aa = pair & 127;
  float v = 0.f;
  if (lane < S49) {
    v  = cosbuf[(size_t)bb * NSIDE + aa * S49 + lane];
    v += cosbuf[(size_t)(128 + aa) * NSIDE + bb * S49 + lane];
  }
  for (int m = 1; m < 64; m <<= 1) v += __shfl_xor(v, m, 64);
  if (lane == 0) out[pair] = v * (1.f / 49.f);
}

// ---------------------------------------------------------------------------
extern "C" void kernel_launch(void* const* d_in, const int* in_sizes, int n_in,
                              void* d_out, int out_size, void* d_ws, size_t ws_size,
                              hipStream_t stream) {
  const float* fa  = (const float*)d_in[0];
  const float* fb  = (const float*)d_in[1];
  const float* W1[3] = {(const float*)d_in[2], (const float*)d_in[4], (const float*)d_in[6]};
  const float* W2[3] = {(const float*)d_in[3], (const float*)d_in[5], (const float*)d_in[7]};
  float* out = (float*)d_out;

  unsigned short* p = (unsigned short*)d_ws;
  unsigned short* Xbf = p;                 p += (size_t)MROWS * CDIM;     // 19.3 MB
  unsigned short* W1T = p;                 p += (size_t)3 * CDIM * CDIM;  // 3.5 MB
  unsigned short* W2T = p;                 p += (size_t)3 * INNER * CDIM; // 0.44 MB
  unsigned short* H   = p;                 p += (size_t)MROWS * CDIM;     // 19.3 MB
  unsigned short* QKV = p;                 p += (size_t)3 * MROWS * INNER;// 7.2 MB
  unsigned short* Vt  = p;                 p += (size_t)256 * INNER * 64; // 3.1 MB
  float* vnorm = (float*)p;                p += (size_t)MROWS * 2;        // 50 KB
  float* cosbuf = (float*)p;                                              // 6.4 MB

  prep_x<<<dim3(12, 128), 256, 0, stream>>>(fa, Xbf, 0);
  prep_x<<<dim3(12, 128), 256, 0, stream>>>(fb, Xbf, 128);
  for (int wdx = 0; wdx < 3; wdx++) {
    prep_wT<<<dim3(24, 24), 256, 0, stream>>>(W1[wdx], W1T + (size_t)wdx * CDIM * CDIM, CDIM, CDIM);
    prep_wT<<<dim3(3, 24), 256, 0, stream>>>(W2[wdx], W2T + (size_t)wdx * INNER * CDIM, CDIM, INNER);
  }
  hipMemsetAsync(Vt, 0, (size_t)256 * INNER * 64 * 2, stream);
  for (int wdx = 0; wdx < 3; wdx++) {
    gemm1b<<<dim3(MROWS / 128, CDIM / 128), 256, 0, stream>>>(
        Xbf, W1T + (size_t)wdx * CDIM * CDIM, H);
    gemm2<<<dim3(MROWS / 64), 256, 0, stream>>>(
        H, W2T + (size_t)wdx * INNER * CDIM, QKV + (size_t)wdx * MROWS * INNER,
        Vt, vnorm, wdx == 2 ? 1 : 0);
  }
  attn2<<<dim3(2 * NSIDE), 256, 0, stream>>>(
      QKV, QKV + (size_t)MROWS * INNER, QKV + (size_t)2 * MROWS * INNER, Vt, vnorm, cosbuf);
  reduce_out<<<dim3(4096), 256, 0, stream>>>(cosbuf, out);
}

// Round 4
// 457.902 us; speedup vs baseline: 4.9784x; 1.2019x over previous
//
#include <hip/hip_runtime.h>
#include <hip/hip_bf16.h>
#include <math.h>

typedef __attribute__((ext_vector_type(8))) short bf16x8;
typedef __attribute__((ext_vector_type(4))) float f32x4;

#define MROWS 12544      // (128+128)*49
#define CDIM 768
#define INNER 96
#define S49 49
#define NSIDE 6272       // 128*49 rows per side
#define SCALE 0.10206207261596577f  // 1/sqrt(96)

__device__ __forceinline__ unsigned short f2bf(float f) {
  union { float f; unsigned u; } v; v.f = f;
  unsigned u = v.u;
  return (unsigned short)((u + 0x7fffu + ((u >> 16) & 1u)) >> 16);
}
__device__ __forceinline__ float bf2f(unsigned short h) {
  union { unsigned u; float f; } v; v.u = ((unsigned)h) << 16;
  return v.f;
}

// async global->LDS, 16B per lane. Dest must be wave-uniform base + lane*16.
__device__ __forceinline__ void gld16(const unsigned short* g, unsigned short* l) {
  __builtin_amdgcn_global_load_lds(
      (const __attribute__((address_space(1))) unsigned int*)(g),
      (__attribute__((address_space(3))) unsigned int*)(l), 16, 0, 0);
}

// ---------------------------------------------------------------------------
// prep_x2: feat[img][C][S] fp32 -> X[(z*128+img)*49+s][C] bf16 (LDS transpose)
// ---------------------------------------------------------------------------
__global__ __launch_bounds__(256) void prep_x2(const float* __restrict__ fa,
                                               const float* __restrict__ fb,
                                               unsigned short* __restrict__ X) {
  __shared__ float T[64][50];
  const int t = threadIdx.x;
  const int ct = blockIdx.x;   // 0..11 (C tiles of 64)
  const int img = blockIdx.y;  // 0..127
  const int z = blockIdx.z;    // side
  const float* feat = z ? fb : fa;
  const float* src = feat + (size_t)img * (CDIM * S49) + (size_t)ct * 64 * S49;
  for (int idx = t; idx < 64 * S49; idx += 256) {
    int cc = idx / S49, s = idx - cc * S49;
    T[cc][s] = src[cc * S49 + s];
  }
  __syncthreads();
  unsigned short* dst = X + (size_t)(z * 128 + img) * S49 * CDIM + ct * 64;
  for (int idx = t; idx < S49 * 64; idx += 256) {
    int s = idx >> 6, cc = idx & 63;
    dst[(size_t)s * CDIM + cc] = f2bf(T[cc][s]);
  }
}

// ---------------------------------------------------------------------------
// prep_w_all: batched transpose of all 6 weights. src[R=768][C] -> dst[C][768].
// W1 jobs: 3 x (24x24 tiles of 32); W2 jobs: 3 x (3x24 tiles).
// ---------------------------------------------------------------------------
__global__ __launch_bounds__(256) void prep_w_all(
    const float* __restrict__ w10, const float* __restrict__ w11,
    const float* __restrict__ w12, const float* __restrict__ w20,
    const float* __restrict__ w21, const float* __restrict__ w22,
    unsigned short* __restrict__ W1T, unsigned short* __restrict__ W2T) {
  __shared__ float T[32][33];
  const int t = threadIdx.x;
  int id = blockIdx.x;
  const float* src;
  unsigned short* dst;
  int C, ctile, rtile;
  if (id < 1728) {
    int wdx = id / 576, tid = id - wdx * 576;
    ctile = tid % 24; rtile = tid / 24;
    src = wdx == 0 ? w10 : (wdx == 1 ? w11 : w12);
    dst = W1T + (size_t)wdx * CDIM * CDIM;
    C = CDIM;
  } else {
    id -= 1728;
    int wdx = id / 72, tid = id - wdx * 72;
    ctile = tid % 3; rtile = tid / 3;
    src = wdx == 0 ? w20 : (wdx == 1 ? w21 : w22);
    dst = W2T + (size_t)wdx * INNER * CDIM;
    C = INNER;
  }
  const int c0 = ctile * 32, r0 = rtile * 32;
  for (int idx = t; idx < 1024; idx += 256) {
    int rr = idx >> 5, cc = idx & 31;
    T[rr][cc] = src[(size_t)(r0 + rr) * C + c0 + cc];
  }
  __syncthreads();
  for (int idx = t; idx < 1024; idx += 256) {
    int rr = idx >> 5, cc = idx & 31;
    dst[(size_t)(c0 + rr) * CDIM + r0 + cc] = f2bf(T[cc][rr]);
  }
}

// ---------------------------------------------------------------------------
// GEMM1 (m97-style): H = relu(X @ W1). M=12544, N=768, K=768.
// 128x128 tile, BK=64, global_load_lds staging, 4 waves each 64x64.
// ---------------------------------------------------------------------------
__global__ __launch_bounds__(256) void gemm1b(const unsigned short* __restrict__ X,
                                              const unsigned short* __restrict__ W1T,
                                              unsigned short* __restrict__ H) {
  __shared__ __align__(16) unsigned short As[128 * 64];
  __shared__ __align__(16) unsigned short Bs[128 * 64];
  const int t = threadIdx.x;
  const int lane = t & 63, w = t >> 6;
  const int lr = lane & 15, lq = lane >> 4;
  const int wm = w & 1, wn = w >> 1;
  const int m0 = blockIdx.x * 128, n0 = blockIdx.y * 128;
  const f32x4 z4 = {0.f, 0.f, 0.f, 0.f};
  f32x4 acc[4][4] = {{z4, z4, z4, z4}, {z4, z4, z4, z4},
                     {z4, z4, z4, z4}, {z4, z4, z4, z4}};

  for (int k0 = 0; k0 < CDIM; k0 += 64) {
    __syncthreads();
#pragma unroll
    for (int j = 0; j < 4; j++) {
      int idx = t + j * 256;               // 0..1023
      int row = idx >> 3, col = (idx & 7) * 8;
      gld16(X + (size_t)(m0 + row) * CDIM + k0 + col, As + idx * 8);
      gld16(W1T + (size_t)(n0 + row) * CDIM + k0 + col, Bs + idx * 8);
    }
    __syncthreads();
#pragma unroll
    for (int ks = 0; ks < 2; ks++) {
      bf16x8 a[4], b[4];
#pragma unroll
      for (int mt = 0; mt < 4; mt++)
        a[mt] = *(const bf16x8*)(As + (wm * 64 + mt * 16 + lr) * 64 + ks * 32 + lq * 8);
#pragma unroll
      for (int nt = 0; nt < 4; nt++)
        b[nt] = *(const bf16x8*)(Bs + (wn * 64 + nt * 16 + lr) * 64 + ks * 32 + lq * 8);
#pragma unroll
      for (int mt = 0; mt < 4; mt++)
#pragma unroll
        for (int nt = 0; nt < 4; nt++)
          acc[mt][nt] = __builtin_amdgcn_mfma_f32_16x16x32_bf16(a[mt], b[nt], acc[mt][nt], 0, 0, 0);
    }
  }
#pragma unroll
  for (int mt = 0; mt < 4; mt++)
#pragma unroll
    for (int nt = 0; nt < 4; nt++)
#pragma unroll
      for (int r = 0; r < 4; r++) {
        int m = m0 + wm * 64 + mt * 16 + lq * 4 + r;
        int n = n0 + wn * 64 + nt * 16 + lr;
        H[(size_t)m * CDIM + n] = f2bf(fmaxf(acc[mt][nt][r], 0.f));
      }
}

// ---------------------------------------------------------------------------
// GEMM2: O = H @ W2. M=12544, N=96, K=768. 64x96 tile (wave = 16 rows x 96).
// mode 0 (Q): write O pre-scaled by 1/sqrt(96).
// mode 1 (K): write only Kpad[img][64][96] (rows 49..63 pre-zeroed).
// mode 2 (V): write O + Vt[img][e][64] (keys zero-padded) + vnorm[m].
// ---------------------------------------------------------------------------
#define LDK 72
__global__ __launch_bounds__(256) void gemm2(const unsigned short* __restrict__ H,
                                             const unsigned short* __restrict__ W2T,
                                             unsigned short* __restrict__ O,
                                             unsigned short* __restrict__ Kpad,
                                             unsigned short* __restrict__ Vt,
                                             float* __restrict__ vnorm,
                                             int mode) {
  __shared__ __align__(16) unsigned short As[64 * LDK];
  __shared__ __align__(16) unsigned short Bs[96 * LDK];
  const int t = threadIdx.x;
  const int lane = t & 63, w = t >> 6;
  const int lr = lane & 15, lq = lane >> 4;
  const int m0 = blockIdx.x * 64;
  const f32x4 z4 = {0.f, 0.f, 0.f, 0.f};
  f32x4 acc[6] = {z4, z4, z4, z4, z4, z4};

  for (int k0 = 0; k0 < CDIM; k0 += 64) {
    __syncthreads();
    for (int c = t; c < 512; c += 256) {
      int r = c >> 3, kc = (c & 7) * 8;
      *(uint4*)(As + r * LDK + kc) = *(const uint4*)(H + (size_t)(m0 + r) * CDIM + k0 + kc);
    }
    for (int c = t; c < 768; c += 256) {
      int r = c >> 3, kc = (c & 7) * 8;
      *(uint4*)(Bs + r * LDK + kc) = *(const uint4*)(W2T + (size_t)r * CDIM + k0 + kc);
    }
    __syncthreads();
#pragma unroll
    for (int kk = 0; kk < 2; kk++) {
      bf16x8 a = *(const bf16x8*)(As + (w * 16 + lr) * LDK + kk * 32 + lq * 8);
#pragma unroll
      for (int nt = 0; nt < 6; nt++) {
        bf16x8 b = *(const bf16x8*)(Bs + (nt * 16 + lr) * LDK + kk * 32 + lq * 8);
        acc[nt] = __builtin_amdgcn_mfma_f32_16x16x32_bf16(a, b, acc[nt], 0, 0, 0);
      }
    }
  }
  float nsq[4] = {0.f, 0.f, 0.f, 0.f};
#pragma unroll
  for (int nt = 0; nt < 6; nt++)
#pragma unroll
    for (int r = 0; r < 4; r++) {
      int m = m0 + w * 16 + lq * 4 + r;
      int e = nt * 16 + lr;
      float v = acc[nt][r];
      int img = m / 49, s = m - img * 49;
      if (mode == 0) {
        O[(size_t)m * INNER + e] = f2bf(v * SCALE);
      } else if (mode == 1) {
        Kpad[(size_t)(img * 64 + s) * INNER + e] = f2bf(v);
      } else {
        O[(size_t)m * INNER + e] = f2bf(v);
        Vt[(size_t)img * (INNER * 64) + e * 64 + s] = f2bf(v);
        nsq[r] += v * v;
      }
    }
  if (mode == 2) {
#pragma unroll
    for (int r = 0; r < 4; r++) {
      float p = nsq[r];
      p += __shfl_xor(p, 1, 16);
      p += __shfl_xor(p, 2, 16);
      p += __shfl_xor(p, 4, 16);
      p += __shfl_xor(p, 8, 16);
      if (lr == 0) vnorm[m0 + w * 16 + lq * 4 + r] = sqrtf(p);
    }
  }
}

// ---------------------------------------------------------------------------
// attn3: block = (dir, 64-query chunk, 16-image f-group). 4 waves x 16 q-rows.
// Q staged once (pre-scaled by 1/sqrt(96) at gemm2); ref V + vnorm in regs.
// Unnormalized, un-max-subtracted softmax (cosine is scale-invariant; scores
// bounded ~|10| so exp is fp32-safe). Padded keys need NO mask: their exp(0)=1
// multiplies zero-padded Vt columns -> exact 0 contribution.
// ---------------------------------------------------------------------------
#define LQS 104   // 52 words: 2-way max bank aliasing
#define LVS 72    // 36 words: 2-way max
__global__ __launch_bounds__(256) void attn3(const unsigned short* __restrict__ Qp,
                                             const unsigned short* __restrict__ Kpad,
                                             const unsigned short* __restrict__ V,
                                             const unsigned short* __restrict__ Vt,
                                             const float* __restrict__ vnorm,
                                             float* __restrict__ cosbuf) {
  __shared__ __align__(16) unsigned short Qs[64 * LQS];
  __shared__ __align__(16) unsigned short Ks[64 * LQS];
  __shared__ __align__(16) unsigned short Vts[96 * LVS];
  __shared__ __align__(16) unsigned short Ps[4][16 * LVS];

  const int t = threadIdx.x;
  const int lane = t & 63, w = t >> 6;
  const int lr = lane & 15, lq = lane >> 4;
  const f32x4 z4 = {0.f, 0.f, 0.f, 0.f};

  int bx = blockIdx.x;
  const int dir = bx / 784; bx -= dir * 784;     // 784 = 98 chunks * 8 fgroups
  const int chunk = bx >> 3, fg = bx & 7;
  const int r0 = chunk * 64;
  const int qbase = dir * NSIDE;

  // hoisted staging indices (row/col within a 64x96 matrix, uint4 chunks)
  int rws[3], cws[3];
#pragma unroll
  for (int i = 0; i < 3; i++) {
    int idx = t + i * 256;
    rws[i] = idx / 12;
    cws[i] = (idx - rws[i] * 12) * 8;
  }
  // ---- stage Q once
#pragma unroll
  for (int i = 0; i < 3; i++)
    *(uint4*)(Qs + rws[i] * LQS + cws[i]) =
        *(const uint4*)(Qp + (size_t)(qbase + r0 + rws[i]) * INNER + cws[i]);

  // ---- reference V rows + vnorm into registers (C-layout mapping)
  float rv[6][4], vnR[4];
#pragma unroll
  for (int r = 0; r < 4; r++) {
    int row = qbase + r0 + w * 16 + lq * 4 + r;
    vnR[r] = fmaxf(vnorm[row], 1e-8f);
#pragma unroll
    for (int et = 0; et < 6; et++)
      rv[et][r] = bf2f(V[(size_t)row * INNER + et * 16 + lr]);
  }

  unsigned short* Pw = &Ps[w][0];
  for (int fi = 0; fi < 16; fi++) {
    const int f = fg * 16 + fi;
    const int kimg = dir == 0 ? 128 + f : f;
    __syncthreads();
    // ---- stage K (pre-padded) and Vt for this image
    const unsigned short* kg = Kpad + (size_t)kimg * (64 * INNER);
    const unsigned short* vg = Vt + (size_t)kimg * (INNER * 64);
#pragma unroll
    for (int i = 0; i < 3; i++)
      *(uint4*)(Ks + rws[i] * LQS + cws[i]) = *(const uint4*)(kg + rws[i] * INNER + cws[i]);
#pragma unroll
    for (int i = 0; i < 3; i++) {
      int idx = t + i * 256;
      int vr = idx >> 3, vc = (idx & 7) * 8;
      *(uint4*)(Vts + vr * LVS + vc) = *(const uint4*)(vg + vr * 64 + vc);
    }
    __syncthreads();
    // ---- scores = Qp @ K^T (already includes 1/sqrt(96))
    f32x4 s4[4] = {z4, z4, z4, z4};
#pragma unroll
    for (int ks = 0; ks < 3; ks++) {
      bf16x8 a = *(const bf16x8*)(Qs + (w * 16 + lr) * LQS + ks * 32 + lq * 8);
#pragma unroll
      for (int kt = 0; kt < 4; kt++) {
        bf16x8 b = *(const bf16x8*)(Ks + (kt * 16 + lr) * LQS + ks * 32 + lq * 8);
        s4[kt] = __builtin_amdgcn_mfma_f32_16x16x32_bf16(a, b, s4[kt], 0, 0, 0);
      }
    }
    // ---- P = exp(scores), bf16, wave-private (no barrier needed)
#pragma unroll
    for (int kt = 0; kt < 4; kt++)
#pragma unroll
      for (int r = 0; r < 4; r++) {
        __hip_bfloat16 h = __float2bfloat16(__expf(s4[kt][r]));
        Pw[(lq * 4 + r) * LVS + kt * 16 + lr] = *(unsigned short*)&h;
      }
    // ---- aligned = P @ V
    f32x4 pv[6] = {z4, z4, z4, z4, z4, z4};
#pragma unroll
    for (int ks = 0; ks < 2; ks++) {
      bf16x8 a = *(const bf16x8*)(Pw + lr * LVS + ks * 32 + lq * 8);
#pragma unroll
      for (int et = 0; et < 6; et++) {
        bf16x8 b = *(const bf16x8*)(Vts + (et * 16 + lr) * LVS + ks * 32 + lq * 8);
        pv[et] = __builtin_amdgcn_mfma_f32_16x16x32_bf16(a, b, pv[et], 0, 0, 0);
      }
    }
    // ---- cosine epilogue, ref in registers
#pragma unroll
    for (int r = 0; r < 4; r++) {
      float d = 0.f, nn = 0.f;
#pragma unroll
      for (int et = 0; et < 6; et++) {
        float al = pv[et][r];
        d += al * rv[et][r];
        nn += al * al;
      }
      d += __shfl_xor(d, 1, 16); d += __shfl_xor(d, 2, 16);
      d += __shfl_xor(d, 4, 16); d += __shfl_xor(d, 8, 16);
      nn += __shfl_xor(nn, 1, 16); nn += __shfl_xor(nn, 2, 16);
      nn += __shfl_xor(nn, 4, 16); nn += __shfl_xor(nn, 8, 16);
      if (lr == 0) {
        float cv = d / (fmaxf(sqrtf(nn), 1e-20f) * vnR[r]);
        cosbuf[(size_t)(dir * 128 + f) * NSIDE + r0 + w * 16 + lq * 4 + r] = cv;
      }
    }
  }
}

// ---------------------------------------------------------------------------
// reduce_out: out[bb*128+aa] = (sum_q cos0[bb][aa*49+q] + cos1[aa][bb*49+q])/49
// ---------------------------------------------------------------------------
__global__ __launch_bounds__(256) void reduce_out(const float* __restrict__ cosbuf,
                                                  float* __restrict__ out) {
  const int t = threadIdx.x, lane = t & 63, wv = t >> 6;
  const int pair = blockIdx.x * 4 + wv;
  const int bb = pair >> 7, aa = pair & 127;
  float v = 0.f;
  if (lane < S49) {
    v  = cosbuf[(size_t)bb * NSIDE + aa * S49 + lane];
    v += cosbuf[(size_t)(128 + aa) * NSIDE + bb * S49 + lane];
  }
  for (int m = 1; m < 64; m <<= 1) v += __shfl_xor(v, m, 64);
  if (lane == 0) out[pair] = v * (1.f / 49.f);
}

// ---------------------------------------------------------------------------
extern "C" void kernel_launch(void* const* d_in, const int* in_sizes, int n_in,
                              void* d_out, int out_size, void* d_ws, size_t ws_size,
                              hipStream_t stream) {
  const float* fa  = (const float*)d_in[0];
  const float* fb  = (const float*)d_in[1];
  const float* W1[3] = {(const float*)d_in[2], (const float*)d_in[4], (const float*)d_in[6]};
  const float* W2[3] = {(const float*)d_in[3], (const float*)d_in[5], (const float*)d_in[7]};
  float* out = (float*)d_out;

  unsigned short* p = (unsigned short*)d_ws;
  unsigned short* Xbf = p;                 p += (size_t)MROWS * CDIM;      // 19.3 MB
  unsigned short* W1T = p;                 p += (size_t)3 * CDIM * CDIM;   // 3.5 MB
  unsigned short* W2T = p;                 p += (size_t)3 * INNER * CDIM;  // 0.44 MB
  unsigned short* H   = p;                 p += (size_t)MROWS * CDIM;      // 19.3 MB
  unsigned short* QKV = p;                 p += (size_t)3 * MROWS * INNER; // 7.2 MB
  unsigned short* Vt  = p;                 p += (size_t)256 * INNER * 64;  // 3.1 MB
  unsigned short* Kpad = p;                p += (size_t)256 * 64 * INNER;  // 3.1 MB
  float* vnorm = (float*)p;                p += (size_t)MROWS * 2;         // 50 KB
  float* cosbuf = (float*)p;                                               // 6.4 MB

  prep_x2<<<dim3(12, 128, 2), 256, 0, stream>>>(fa, fb, Xbf);
  prep_w_all<<<dim3(1944), 256, 0, stream>>>(W1[0], W1[1], W1[2],
                                             W2[0], W2[1], W2[2], W1T, W2T);
  hipMemsetAsync(Vt, 0, (size_t)256 * INNER * 64 * 2, stream);
  hipMemsetAsync(Kpad, 0, (size_t)256 * 64 * INNER * 2, stream);
  for (int wdx = 0; wdx < 3; wdx++) {
    gemm1b<<<dim3(MROWS / 128, CDIM / 128), 256, 0, stream>>>(
        Xbf, W1T + (size_t)wdx * CDIM * CDIM, H);
    gemm2<<<dim3(MROWS / 64), 256, 0, stream>>>(
        H, W2T + (size_t)wdx * INNER * CDIM, QKV + (size_t)wdx * MROWS * INNER,
        Kpad, Vt, vnorm, wdx);
  }
  attn3<<<dim3(2 * 784), 256, 0, stream>>>(
      QKV, Kpad, QKV + (size_t)2 * MROWS * INNER, Vt, vnorm, cosbuf);
  reduce_out<<<dim3(4096), 256, 0, stream>>>(cosbuf, out);
}